// Round 1
// baseline (161.278 us; speedup 1.0000x reference)
//
#include <hip/hip_runtime.h>

#define B_   4
#define NQ_  512
#define NK_  512
#define D_   512
#define H_   128

__device__ __forceinline__ float fexp2(float x) { return __builtin_amdgcn_exp2f(x); }
__device__ __forceinline__ float frcp(float x)  { return __builtin_amdgcn_rcpf(x); }

// ---------------------------------------------------------------------------
// Kernel A: P = X @ W   (X: (2048,512), W: (512,128), P: (2048,128)), fp32.
// blockIdx.z = 0 -> Qp, 1 -> Kp. 32 rows x 128 cols per block, 256 threads,
// 4x4 accumulators per thread, K staged in 32-chunks through LDS.
// ---------------------------------------------------------------------------
__global__ __launch_bounds__(256) void proj_kernel(
    const float* __restrict__ Q, const float* __restrict__ K,
    const float* __restrict__ Wq, const float* __restrict__ Wk,
    float* __restrict__ Qp, float* __restrict__ Kp)
{
    const int z = blockIdx.z;
    const float* __restrict__ X = z ? K  : Q;
    const float* __restrict__ W = z ? Wk : Wq;
    float* __restrict__ P       = z ? Kp : Qp;

    const int r0 = blockIdx.x * 32;
    const int t  = threadIdx.x;
    const int cg = t & 31;   // cols 4*cg .. 4*cg+3
    const int rg = t >> 5;   // rows 4*rg .. 4*rg+3

    __shared__ float Xt[32][36];    // [k][row], transposed, pad 36 (16B-aligned rows)
    __shared__ float Wl[32][128];   // [k][col]

    float acc[4][4] = {};

    for (int kk = 0; kk < D_; kk += 32) {
        // stage X tile (32 rows x 32 k), transposed into LDS
        {
            const int row = t >> 3;          // 0..31
            const int kq  = (t & 7) * 4;     // 0,4,..,28
            const float4 v = *reinterpret_cast<const float4*>(
                X + (size_t)(r0 + row) * D_ + kk + kq);
            Xt[kq + 0][row] = v.x;
            Xt[kq + 1][row] = v.y;
            Xt[kq + 2][row] = v.z;
            Xt[kq + 3][row] = v.w;
        }
        // stage W tile (32 k x 128 cols), natural layout
        #pragma unroll
        for (int p = 0; p < 4; ++p) {
            const int idx = p * 1024 + t * 4;   // flat float index in 32x128 tile
            *reinterpret_cast<float4*>(&Wl[0][0] + idx) =
                *reinterpret_cast<const float4*>(W + (size_t)kk * H_ + idx);
        }
        __syncthreads();

        #pragma unroll
        for (int k = 0; k < 32; ++k) {
            const float4 xv = *reinterpret_cast<const float4*>(&Xt[k][rg * 4]);
            const float4 wv = *reinterpret_cast<const float4*>(&Wl[k][cg * 4]);
            const float xa[4] = {xv.x, xv.y, xv.z, xv.w};
            const float wa[4] = {wv.x, wv.y, wv.z, wv.w};
            #pragma unroll
            for (int r = 0; r < 4; ++r)
                #pragma unroll
                for (int c = 0; c < 4; ++c)
                    acc[r][c] = fmaf(xa[r], wa[c], acc[r][c]);
        }
        __syncthreads();
    }

    #pragma unroll
    for (int r = 0; r < 4; ++r) {
        float4 v = make_float4(acc[r][0], acc[r][1], acc[r][2], acc[r][3]);
        *reinterpret_cast<float4*>(
            P + (size_t)(r0 + rg * 4 + r) * H_ + cg * 4) = v;
    }
}

// ---------------------------------------------------------------------------
// Kernel B: scores + masked softmax.
// Block: 4 q-rows x all 512 k for one batch. 256 threads.
//   score'[q,k] = sum_h (-2*wv[h]) / (1 + exp2((Qp+Kp)*2*log2e))
// (the additive constant sum_h wv[h] cancels in softmax, so it is dropped;
//  Qp/Kp are pre-scaled by 2*log2e at LDS staging time)
// Then wave-per-row softmax with mask k < valid_lens[b]; weights -> Wt (fp32).
// ---------------------------------------------------------------------------
__global__ __launch_bounds__(256) void score_softmax_kernel(
    const float* __restrict__ Qp, const float* __restrict__ Kp,
    const float* __restrict__ wv, const int* __restrict__ valid_lens,
    float* __restrict__ Wt)
{
    const int b  = blockIdx.y;
    const int q0 = blockIdx.x * 4;
    const int t  = threadIdx.x;

    __shared__ __align__(16) float4 Qs[4][33];   // [q][h4], pre-scaled
    __shared__ __align__(16) float4 Ks[64][33];  // [k][h4], pre-scaled, pad 33
    __shared__ __align__(16) float  Sc[4][520];  // scores
    __shared__ __align__(16) float  wvn[H_];     // -2*wv[h]

    const float C2 = 2.88539008177792681472f;    // 2*log2(e)

    if (t < 128) {
        const int q  = t >> 5;
        const int h4 = t & 31;
        float4 v = *reinterpret_cast<const float4*>(
            Qp + ((size_t)(b * NQ_ + q0 + q)) * H_ + h4 * 4);
        v.x *= C2; v.y *= C2; v.z *= C2; v.w *= C2;
        Qs[q][h4] = v;
        wvn[t] = -2.0f * wv[t];
    }

    const int q  = t >> 6;   // 0..3
    const int kl = t & 63;   // 0..63

    for (int kc = 0; kc < 8; ++kc) {
        __syncthreads();   // also covers Qs/wvn staging on first iteration
        // stage 64 k-rows of Kp (pre-scaled): 2048 float4 / 256 threads = 8 each
        #pragma unroll
        for (int p = 0; p < 8; ++p) {
            const int idx = p * 256 + t;     // float4 index 0..2047
            const int kr  = idx >> 5;        // 0..63
            const int h4  = idx & 31;
            float4 v = *reinterpret_cast<const float4*>(
                Kp + ((size_t)(b * NK_) + kc * 64 + kr) * H_ + h4 * 4);
            v.x *= C2; v.y *= C2; v.z *= C2; v.w *= C2;
            Ks[kr][h4] = v;
        }
        __syncthreads();

        float s = 0.0f;
        #pragma unroll
        for (int h4 = 0; h4 < 32; ++h4) {
            const float4 qv = Qs[q][h4];
            const float4 kv = Ks[kl][h4];
            const float4 wn = *reinterpret_cast<const float4*>(&wvn[h4 * 4]);
            s = fmaf(wn.x, frcp(1.0f + fexp2(qv.x + kv.x)), s);
            s = fmaf(wn.y, frcp(1.0f + fexp2(qv.y + kv.y)), s);
            s = fmaf(wn.z, frcp(1.0f + fexp2(qv.z + kv.z)), s);
            s = fmaf(wn.w, frcp(1.0f + fexp2(qv.w + kv.w)), s);
        }
        Sc[q][kc * 64 + kl] = s;
    }
    __syncthreads();

    // softmax: wave w handles row q=w; 8 elems per lane
    {
        const int lane = t & 63;
        const int row  = t >> 6;
        const int vl   = valid_lens[b];

        float vals[8];
        float m = -1e30f;
        #pragma unroll
        for (int j = 0; j < 8; ++j) {
            const int k = j * 64 + lane;
            float sv = Sc[row][k];
            sv = (k < vl) ? sv : -1e30f;
            vals[j] = sv;
            m = fmaxf(m, sv);
        }
        #pragma unroll
        for (int off = 32; off >= 1; off >>= 1)
            m = fmaxf(m, __shfl_xor(m, off, 64));

        const float L2E = 1.44269504088896340736f;
        float e[8];
        float sum = 0.0f;
        #pragma unroll
        for (int j = 0; j < 8; ++j) {
            e[j] = fexp2((vals[j] - m) * L2E);   // masked -> exp2(-huge) = 0
            sum += e[j];
        }
        #pragma unroll
        for (int off = 32; off >= 1; off >>= 1)
            sum += __shfl_xor(sum, off, 64);

        const float inv = frcp(sum);
        float* __restrict__ dst =
            Wt + ((size_t)(b * NQ_ + q0 + row)) * NK_;
        #pragma unroll
        for (int j = 0; j < 8; ++j)
            dst[j * 64 + lane] = e[j] * inv;
    }
}

// ---------------------------------------------------------------------------
// Kernel C: O[b] = Wt[b] @ V[b], (512x512)@(512x512) fp32, 4 batches.
// 64x64 tile / block, 256 threads, 4x4 acc/thread, k staged in 16-chunks.
// ---------------------------------------------------------------------------
__global__ __launch_bounds__(256) void av_gemm_kernel(
    const float* __restrict__ Wt, const float* __restrict__ V,
    float* __restrict__ O)
{
    const int b  = blockIdx.z;
    const int r0 = blockIdx.y * 64;   // q rows
    const int c0 = blockIdx.x * 64;   // v cols
    const int t  = threadIdx.x;
    const int cg = t & 15;            // cols 4*cg..
    const int rg = t >> 4;            // rows 4*rg..

    __shared__ float At[16][68];   // [k][row] transposed
    __shared__ float Bl[16][68];   // [k][col]

    const float* __restrict__ Wb = Wt + (size_t)b * NQ_ * NK_;
    const float* __restrict__ Vb = V  + (size_t)b * NK_ * D_;

    float acc[4][4] = {};

    for (int kk = 0; kk < NK_; kk += 16) {
        {
            const int row = t >> 2;         // 0..63
            const int kq  = (t & 3) * 4;    // 0,4,8,12
            const float4 v = *reinterpret_cast<const float4*>(
                Wb + (size_t)(r0 + row) * NK_ + kk + kq);
            At[kq + 0][row] = v.x;
            At[kq + 1][row] = v.y;
            At[kq + 2][row] = v.z;
            At[kq + 3][row] = v.w;
        }
        {
            const int kr = t >> 4;          // 0..15
            const int cq = (t & 15) * 4;    // 0..60
            *reinterpret_cast<float4*>(&Bl[kr][cq]) =
                *reinterpret_cast<const float4*>(
                    Vb + (size_t)(kk + kr) * D_ + c0 + cq);
        }
        __syncthreads();

        #pragma unroll
        for (int k = 0; k < 16; ++k) {
            const float4 av = *reinterpret_cast<const float4*>(&At[k][rg * 4]);
            const float4 bv = *reinterpret_cast<const float4*>(&Bl[k][cg * 4]);
            const float aa[4] = {av.x, av.y, av.z, av.w};
            const float bb[4] = {bv.x, bv.y, bv.z, bv.w};
            #pragma unroll
            for (int r = 0; r < 4; ++r)
                #pragma unroll
                for (int c = 0; c < 4; ++c)
                    acc[r][c] = fmaf(aa[r], bb[c], acc[r][c]);
        }
        __syncthreads();
    }

    #pragma unroll
    for (int r = 0; r < 4; ++r) {
        float4 v = make_float4(acc[r][0], acc[r][1], acc[r][2], acc[r][3]);
        *reinterpret_cast<float4*>(
            O + ((size_t)b * NQ_ + r0 + rg * 4 + r) * D_ + c0 + cg * 4) = v;
    }
}

extern "C" void kernel_launch(void* const* d_in, const int* in_sizes, int n_in,
                              void* d_out, int out_size, void* d_ws, size_t ws_size,
                              hipStream_t stream) {
    (void)in_sizes; (void)n_in; (void)out_size; (void)ws_size;

    const float* Q   = (const float*)d_in[0];
    const float* K   = (const float*)d_in[1];
    const float* V   = (const float*)d_in[2];
    const float* Wq  = (const float*)d_in[3];
    const float* Wk  = (const float*)d_in[4];
    const float* wv  = (const float*)d_in[5];
    const int*   vl  = (const int*)d_in[6];
    float* out = (float*)d_out;

    float* ws = (float*)d_ws;
    float* Qp = ws;                       // 4*512*128 = 262144 floats
    float* Kp = ws + 262144;              // 262144 floats
    float* Wt = ws + 524288;              // 4*512*512 = 1048576 floats

    proj_kernel<<<dim3(64, 1, 2), 256, 0, stream>>>(Q, K, Wq, Wk, Qp, Kp);
    score_softmax_kernel<<<dim3(NQ_ / 4, B_), 256, 0, stream>>>(Qp, Kp, wv, vl, Wt);
    av_gemm_kernel<<<dim3(8, 8, 4), 256, 0, stream>>>(Wt, V, out);
}